// Round 9
// baseline (102.685 us; speedup 1.0000x reference)
//
#include <hip/hip_runtime.h>
#include <stdint.h>

// IDXST(4096x4096): y[r][k] = sum_n x[r][n] sin(pi*n*(2k+1)/8192).
// R14: R13 (balanced 256x128 tiles, 4Mx2N wave grid, 80KB LDS) with phases
// MERGED 4->2 per K-tile. R6/R13 phase accounting shows a ~450-760cyc
// CONSTANT per-phase overhead (barrier pair + lgkm drain + read latency)
// independent of traffic (R13's -20% LDS reads bought only 2%); m201's
// efficiency comes from amortizing that cost over 16 MFMA/wave/phase.
// Fused phase 1: reads A(h0)+B(both) [12 b128], stage A[t+1]h0, 16 MFMA
// (q00,q01). Fused phase 2: reads A(h1) [4 b128], stage A[t+1]h1 + B[t+1],
// 16 MFMA (q11,q10), vmcnt(0) drain. 2 barrier pairs per K-tile (was 4).
// Hazards: B[t] last read in P1 (sealed by P1 trailing barrier) -> B[t+1]
// staged P2 ok; A[t+1] staged into opposite buffer; vmcnt(0) at P2-end
// drains all 6 next-tile loads before P3 reads them.
// ws (44 MB): xo 16 | xee 8 | xeo 8 | Bo 8 | Bp 2 | Bq 2.

#define NN 4096

typedef __attribute__((ext_vector_type(8))) short short8;
typedef __attribute__((ext_vector_type(4))) float f32x4;

__device__ __forceinline__ unsigned short f2bf(float f) {
  unsigned int u = __float_as_uint(f);
  u += 0x7fffu + ((u >> 16) & 1u);
  return (unsigned short)(u >> 16);
}

__device__ __forceinline__ void async_load16(const void* g, void* lds) {
  __builtin_amdgcn_global_load_lds(
      (const __attribute__((address_space(1))) unsigned int*)g,
      (__attribute__((address_space(3))) unsigned int*)lds, 16, 0, 0);
}

#define NXS (NN * NN / 8)        // 2M x-split threads (8 floats each)
#define NBO (2048 * 2048 / 4)    // 1M Bo threads
#define NBP (1024 * 1024 / 4)    // 256K Bp threads (Bq same)

// prep: xo[r][m]=x[r][2m+1]; xee[r][t]=x[r][4t]; xeo[r][t]=x[r][4t+2];
// Bo[c][m]=sin(pi(2m+1)(2c+1)/8192); Bp[c][t]=sin(pi*t*(2c+1)/2048);
// Bq[c][t]=sin(pi(2t+1)(2c+1)/4096)
__global__ void prep_kernel(const float* __restrict__ x,
                            unsigned short* __restrict__ xo,
                            unsigned short* __restrict__ xee,
                            unsigned short* __restrict__ xeo,
                            unsigned short* __restrict__ Bo,
                            unsigned short* __restrict__ Bp,
                            unsigned short* __restrict__ Bq) {
  int gi = blockIdx.x * blockDim.x + threadIdx.x;
  if (gi < NXS) {
    int g = gi & 511;            // 8-float group in row
    int r = gi >> 9;
    const float4* src = (const float4*)(x + (size_t)r * NN + g * 8);
    float4 v0 = src[0], v1 = src[1];    // n = 8g+0..3, 8g+4..7
    ushort4 ov;                          // odd n -> m = 4g..4g+3
    ov.x = f2bf(v0.y); ov.y = f2bf(v0.w); ov.z = f2bf(v1.y); ov.w = f2bf(v1.w);
    *(ushort4*)&xo[(size_t)r * 2048 + g * 4] = ov;
    unsigned int ee = ((unsigned)f2bf(v1.x) << 16) | f2bf(v0.x);  // t=2g,2g+1
    *(unsigned int*)&xee[(size_t)r * 1024 + g * 2] = ee;
    unsigned int eo = ((unsigned)f2bf(v1.z) << 16) | f2bf(v0.z);
    *(unsigned int*)&xeo[(size_t)r * 1024 + g * 2] = eo;
  } else if (gi < NXS + NBO) {
    int i = gi - NXS;
    int m0 = (i & 511) * 4;
    int c = i >> 9;
    unsigned int tw = 2u * (unsigned)c + 1u;
    const float sc = 3.14159265358979323846f / 8192.0f;
    ushort4 o; unsigned int ph;
    ph = ((unsigned)(2 * (m0 + 0) + 1) * tw) & 16383u; o.x = f2bf(__sinf((float)ph * sc));
    ph = ((unsigned)(2 * (m0 + 1) + 1) * tw) & 16383u; o.y = f2bf(__sinf((float)ph * sc));
    ph = ((unsigned)(2 * (m0 + 2) + 1) * tw) & 16383u; o.z = f2bf(__sinf((float)ph * sc));
    ph = ((unsigned)(2 * (m0 + 3) + 1) * tw) & 16383u; o.w = f2bf(__sinf((float)ph * sc));
    *(ushort4*)&Bo[(size_t)c * 2048 + m0] = o;
  } else if (gi < NXS + NBO + NBP) {
    int i = gi - NXS - NBO;
    int t0 = (i & 255) * 4;
    int c = i >> 8;
    unsigned int tw = 2u * (unsigned)c + 1u;
    const float sc = 3.14159265358979323846f / 2048.0f;
    ushort4 o; unsigned int ph;
    ph = ((unsigned)(t0 + 0) * tw) & 4095u; o.x = f2bf(__sinf((float)ph * sc));
    ph = ((unsigned)(t0 + 1) * tw) & 4095u; o.y = f2bf(__sinf((float)ph * sc));
    ph = ((unsigned)(t0 + 2) * tw) & 4095u; o.z = f2bf(__sinf((float)ph * sc));
    ph = ((unsigned)(t0 + 3) * tw) & 4095u; o.w = f2bf(__sinf((float)ph * sc));
    *(ushort4*)&Bp[(size_t)c * 1024 + t0] = o;
  } else {
    int i = gi - NXS - NBO - NBP;
    int t0 = (i & 255) * 4;
    int c = i >> 8;
    unsigned int tw = 2u * (unsigned)c + 1u;
    const float sc = 3.14159265358979323846f / 4096.0f;
    ushort4 o; unsigned int ph;
    ph = ((unsigned)(2 * (t0 + 0) + 1) * tw) & 8191u; o.x = f2bf(__sinf((float)ph * sc));
    ph = ((unsigned)(2 * (t0 + 1) + 1) * tw) & 8191u; o.y = f2bf(__sinf((float)ph * sc));
    ph = ((unsigned)(2 * (t0 + 2) + 1) * tw) & 8191u; o.z = f2bf(__sinf((float)ph * sc));
    ph = ((unsigned)(2 * (t0 + 3) + 1) * tw) & 8191u; o.w = f2bf(__sinf((float)ph * sc));
    *(ushort4*)&Bq[(size_t)c * 1024 + t0] = o;
  }
}

// ---- 2-phase-per-K-tile 256x128 GEMM, 80KB LDS, wave grid 4Mx2N ----------
// LDS ushort offsets: A buf0 [0,16384), A buf1 [16384,32768), B [32768,40960).
#define PH_BAR  __builtin_amdgcn_s_barrier()
#define W_LGKM0 asm volatile("s_waitcnt lgkmcnt(0)" ::: "memory")
#define W_VM0   asm volatile("s_waitcnt vmcnt(0)" ::: "memory")
#define PRIO1   __builtin_amdgcn_s_setprio(1)
#define PRIO0   __builtin_amdgcn_s_setprio(0)

// Stage A half-tile (128 rows x 64 k = 16KB, 2 loads/thread). Linear LDS dest;
// source chunk pre-swizzled by the chunk^(row&7) involution the reads apply.
#define STAGEA(prow0, koff, off) do {                                           \
    const unsigned short* _s =                                                  \
        A + (size_t)((prow0) + st_r) * K + (koff) + st_c;                       \
    async_load16(_s, &lds[(off) + tid * 8]);                                    \
    async_load16(_s + (size_t)64 * K, &lds[(off) + 4096 + tid * 8]);            \
  } while (0)

// Stage B half-tile (64 rows x 64 k = 8KB, 1 load/thread).
#define STAGEB(pcol0, koff, off) do {                                           \
    const unsigned short* _s =                                                  \
        Bm + (size_t)((pcol0) + st_r) * K + (koff) + st_c;                      \
    async_load16(_s, &lds[(off) + tid * 8]);                                    \
  } while (0)

// A-frags for row-half mh (32 rows = frags mh*2, mh*2+1) of buffer b.
// Wave's rows: wm*64 + mh*32 + i*16 + lr. 4 ds_read_b128.
#define LOADA(b, mh) do {                                                       \
    const int _ab = (b) * 16384 + wm * 4096 + (mh) * 2048 + lr * 64;            \
    _Pragma("unroll") for (int _i = 0; _i < 2; ++_i) {                          \
      av[(mh) * 2 + _i][0] = *(const short8*)&lds[_ab + _i * 1024 + cA0];       \
      av[(mh) * 2 + _i][1] = *(const short8*)&lds[_ab + _i * 1024 + cA1];       \
    }                                                                           \
  } while (0)

// B-frags for col-half nh (32 cols) into SET[2][2]. Wave's cols:
// wn*64 + nh*32 + j*16 + lr. 4 ds_read_b128.
#define LOADB(SET, nh) do {                                                     \
    const int _bb = 32768 + wn * 4096 + (nh) * 2048 + lr * 64;                  \
    _Pragma("unroll") for (int _j = 0; _j < 2; ++_j) {                          \
      SET[_j][0] = *(const short8*)&lds[_bb + _j * 1024 + cA0];                 \
      SET[_j][1] = *(const short8*)&lds[_bb + _j * 1024 + cA1];                 \
    }                                                                           \
  } while (0)

// One 32x32 C-quadrant x K=64: 8 MFMA.
#define MMAQ(BS, mh, nh) do {                                                   \
    _Pragma("unroll") for (int _k = 0; _k < 2; ++_k)                            \
    _Pragma("unroll") for (int _i = 0; _i < 2; ++_i)                            \
    _Pragma("unroll") for (int _j = 0; _j < 2; ++_j)                            \
      acc[(mh) * 2 + _i][(nh) * 2 + _j] =                                       \
          __builtin_amdgcn_mfma_f32_16x16x32_bf16(                              \
              av[(mh) * 2 + _i][_k], BS[_j][_k],                                \
              acc[(mh) * 2 + _i][(nh) * 2 + _j], 0, 0, 0);                      \
  } while (0)

__global__ __launch_bounds__(512) void gemm3_kernel(
    const unsigned short* __restrict__ xo,
    const unsigned short* __restrict__ xee,
    const unsigned short* __restrict__ xeo,
    const unsigned short* __restrict__ Bo,
    const unsigned short* __restrict__ Bp,
    const unsigned short* __restrict__ Bq,
    float* __restrict__ out) {
  __shared__ __align__(16) unsigned short lds[40960];   // 80 KiB

  // bx 0..255: U (K=2048) -> breadth-first round 1 puts one U on every CU.
  const int bx = blockIdx.x;
  const unsigned short* A;
  const unsigned short* Bm;
  int K, row0, ncol0, col0;
  if (bx < 256) {
    A = xo;  Bm = Bo; K = 2048;
    row0 = (bx & 15) * 256; ncol0 = (bx >> 4) * 128; col0 = ncol0;
  } else if (bx < 384) {
    int b = bx - 256;
    A = xee; Bm = Bp; K = 1024;
    row0 = (b & 15) * 256; ncol0 = (b >> 4) * 128; col0 = 2048 + ncol0;
  } else {
    int b = bx - 384;
    A = xeo; Bm = Bq; K = 1024;
    row0 = (b & 15) * 256; ncol0 = (b >> 4) * 128; col0 = 3072 + ncol0;
  }
  const int NT = K >> 6;           // K-tiles of 64 (32 for U, 16 for P/Q)

  const int tid = threadIdx.x;
  const int lane = tid & 63;
  const int wave = tid >> 6;
  const int wm = wave >> 1;        // 0..3 : 64-row strip of C
  const int wn = wave & 1;         // 0..1 : 64-col strip of C
  const int lr = lane & 15, kq = lane >> 4;
  const int st_r = tid >> 3;                         // staging row 0..63
  const int st_c = ((tid & 7) ^ (st_r & 7)) * 8;     // pre-swizzled src chunk
  const int cA0 = (kq ^ (lr & 7)) * 8;               // swizzled ds_read chunks
  const int cA1 = ((4 + kq) ^ (lr & 7)) * 8;

  f32x4 acc[4][4];
#pragma unroll
  for (int i = 0; i < 4; ++i)
#pragma unroll
    for (int j = 0; j < 4; ++j)
      acc[i][j] = (f32x4){0.f, 0.f, 0.f, 0.f};
  short8 av[4][2], bv0[2][2], bv1[2][2];

  // Prologue: tile0 A -> buf0, B[0] -> B region; full drain.
  STAGEA(row0,       0, 0);
  STAGEA(row0 + 128, 0, 8192);
  STAGEB(ncol0,      0, 32768);
  STAGEB(ncol0 + 64, 0, 36864);
  W_VM0; PH_BAR;

  const int NITER = NT >> 1;
  for (int it = 0; it < NITER - 1; ++it) {
    const int t64 = it << 7;       // k-offset of tile t = 2*it
    // ---- tile t (buf0) ----
    // P1: reads A(0,h0) + B both halves (12 b128); stage A[t+1]h0 -> buf1;
    //     16 MFMA (q00, q01).
    LOADA(0, 0); LOADB(bv0, 0); LOADB(bv1, 1);
    STAGEA(row0, t64 + 64, 16384);
    PH_BAR; W_LGKM0;
    PRIO1; MMAQ(bv0, 0, 0); MMAQ(bv1, 0, 1); PRIO0; PH_BAR;
    // P2: reads A(0,h1) (4 b128); stage A[t+1]h1 -> buf1 + B[t+1] (B[t] reads
    //     sealed by P1 trailing barrier); 16 MFMA (q11, q10); drain tile t+1.
    LOADA(0, 1);
    STAGEA(row0 + 128, t64 + 64, 24576);
    STAGEB(ncol0,      t64 + 64, 32768);
    STAGEB(ncol0 + 64, t64 + 64, 36864);
    PH_BAR; W_LGKM0;
    PRIO1; MMAQ(bv1, 1, 1); MMAQ(bv0, 1, 0); PRIO0; W_VM0; PH_BAR;
    // ---- tile t+1 (buf1) ----
    // P3: reads A(1,h0) + B; stage A[t+2]h0 -> buf0; 16 MFMA.
    LOADA(1, 0); LOADB(bv0, 0); LOADB(bv1, 1);
    STAGEA(row0, t64 + 128, 0);
    PH_BAR; W_LGKM0;
    PRIO1; MMAQ(bv0, 0, 0); MMAQ(bv1, 0, 1); PRIO0; PH_BAR;
    // P4: reads A(1,h1); stage A[t+2]h1 -> buf0 + B[t+2]; 16 MFMA; drain.
    LOADA(1, 1);
    STAGEA(row0 + 128, t64 + 128, 8192);
    STAGEB(ncol0,      t64 + 128, 32768);
    STAGEB(ncol0 + 64, t64 + 128, 36864);
    PH_BAR; W_LGKM0;
    PRIO1; MMAQ(bv1, 1, 1); MMAQ(bv0, 1, 0); PRIO0; W_VM0; PH_BAR;
  }

  // Peeled last pair (tiles NT-2 -> buf0, NT-1 -> buf1): stage only A[NT-1]
  // and B[NT-1] during the first tile; tail barrier-free (no LDS writes after
  // the last barrier).
  {
    const int t64 = (NT - 2) << 6;
    LOADA(0, 0); LOADB(bv0, 0); LOADB(bv1, 1);
    STAGEA(row0, t64 + 64, 16384);
    PH_BAR; W_LGKM0;
    PRIO1; MMAQ(bv0, 0, 0); MMAQ(bv1, 0, 1); PRIO0; PH_BAR;
    LOADA(0, 1);
    STAGEA(row0 + 128, t64 + 64, 24576);
    STAGEB(ncol0,      t64 + 64, 32768);
    STAGEB(ncol0 + 64, t64 + 64, 36864);
    PH_BAR; W_LGKM0;
    PRIO1; MMAQ(bv1, 1, 1); MMAQ(bv0, 1, 0); PRIO0; W_VM0; PH_BAR;
    // tile NT-1 (buf1)
    LOADA(1, 0); LOADB(bv0, 0); LOADB(bv1, 1);
    W_LGKM0; PRIO1; MMAQ(bv0, 0, 0); MMAQ(bv1, 0, 1); PRIO0;
    LOADA(1, 1);
    W_LGKM0; PRIO1; MMAQ(bv1, 1, 1); MMAQ(bv0, 1, 0); PRIO0;
  }

  // C/D layout: col=lane&15, row=quad*4+reg
#pragma unroll
  for (int i = 0; i < 4; ++i)
#pragma unroll
    for (int j = 0; j < 4; ++j)
#pragma unroll
      for (int r = 0; r < 4; ++r) {
        int row = row0 + wm * 64 + i * 16 + kq * 4 + r;
        int col = col0 + wn * 64 + j * 16 + lr;
        out[(size_t)row * NN + col] = acc[i][j][r];
      }
}

// In-place combine, both fold levels. Row layout on entry:
// [0:2048)=u, [2048:3072)=p, [3072:4096)=q.
// v[k']=p+q, v[2047-k']=q-p (k'<1024); y[k]=v[k]+u[k], y[4095-k]=u[k]-v[k].
__global__ void combine_kernel(float* __restrict__ out) {
  int t = blockIdx.x * blockDim.x + threadIdx.x;   // 4096 rows * 128 threads
  int r = t >> 7;
  int k0 = (t & 127) * 4;                          // [0,512)
  float* row = out + (size_t)r * NN;
  float U0[4], U1[4], U2[4], U3[4], P0[4], P1[4], Q0[4], Q1[4];
  *(float4*)U0 = *(float4*)&row[k0];          // u[k0+e]
  *(float4*)U1 = *(float4*)&row[1020 - k0];   // u[1023-k'] rev
  *(float4*)U2 = *(float4*)&row[1024 + k0];   // u[1024+k0+e]
  *(float4*)U3 = *(float4*)&row[2044 - k0];   // u[2047-k'] rev
  *(float4*)P0 = *(float4*)&row[2048 + k0];   // p[k0+e]
  *(float4*)P1 = *(float4*)&row[3068 - k0];   // p[1023-k'] rev
  *(float4*)Q0 = *(float4*)&row[3072 + k0];   // q[k0+e]
  *(float4*)Q1 = *(float4*)&row[4092 - k0];   // q[1023-k'] rev
  float YA[4], YB[4], YC[4], YD[4], YE[4], YF[4], YG[4], YH[4];
#pragma unroll
  for (int e = 0; e < 4; ++e) {
    float v1 = P0[e] + Q0[e];        // v[k']
    float v2 = Q0[e] - P0[e];        // v[2047-k']
    float um = U3[3 - e];            // u[2047-k']
    YA[e] = v1 + U0[e];              // y[k']
    YB[3 - e] = U0[e] - v1;          // y[4095-k']
    YC[3 - e] = v2 + um;             // y[2047-k']
    YD[e] = um - v2;                 // y[2048+k']
    float pm = P1[3 - e], qm = Q1[3 - e];
    float w1 = pm + qm;              // v[1023-k']
    float w2 = qm - pm;              // v[1024+k']
    float umm = U1[3 - e];           // u[1023-k']
    YE[3 - e] = w1 + umm;            // y[1023-k']
    YF[e] = umm - w1;                // y[3072+k']
    YG[e] = w2 + U2[e];              // y[1024+k']
    YH[3 - e] = U2[e] - w2;          // y[3071-k']
  }
  *(float4*)&row[k0] = *(float4*)YA;
  *(float4*)&row[4092 - k0] = *(float4*)YB;
  *(float4*)&row[2044 - k0] = *(float4*)YC;
  *(float4*)&row[2048 + k0] = *(float4*)YD;
  *(float4*)&row[1020 - k0] = *(float4*)YE;
  *(float4*)&row[3072 + k0] = *(float4*)YF;
  *(float4*)&row[1024 + k0] = *(float4*)YG;
  *(float4*)&row[3068 - k0] = *(float4*)YH;
}

extern "C" void kernel_launch(void* const* d_in, const int* in_sizes, int n_in,
                              void* d_out, int out_size, void* d_ws, size_t ws_size,
                              hipStream_t stream) {
  const float* x = (const float*)d_in[0];
  float* out = (float*)d_out;
  unsigned short* xo  = (unsigned short*)d_ws;            // 16 MB
  unsigned short* xee = xo + (size_t)NN * 2048;           // 8 MB
  unsigned short* xeo = xee + (size_t)NN * 1024;          // 8 MB
  unsigned short* Bo  = xeo + (size_t)NN * 1024;          // 8 MB
  unsigned short* Bp  = Bo + (size_t)2048 * 2048;         // 2 MB
  unsigned short* Bq  = Bp + (size_t)1024 * 1024;         // 2 MB -> 44 MB total

  int prep_threads = NXS + NBO + 2 * NBP;
  prep_kernel<<<prep_threads / 256, 256, 0, stream>>>(x, xo, xee, xeo, Bo, Bp, Bq);

  gemm3_kernel<<<512, 512, 0, stream>>>(xo, xee, xeo, Bo, Bp, Bq, out);

  combine_kernel<<<NN * 128 / 256, 256, 0, stream>>>(out);
}

// Round 10
// 79.577 us; speedup vs baseline: 1.2904x; 1.2904x over previous
//
#include <hip/hip_runtime.h>
#include <stdint.h>

// IDXST(4096x4096): y[r][k] = sum_n x[r][n] sin(pi*n*(2k+1)/8192).
// R15: QUAD-CLOSED GRID — the combine pass is deleted. Each block owns a
// closed quad-set of output columns for k' in [c0,c0+32), c0=(bx>>4)*32:
//   U seg:  256x128, K=2048 (u at strips S1=k', S2=1023-k', S3=1024+k',
//           S4=2047-k'), staged col order [S1 fwd|S4 rev] + [S2 rev|S3 fwd]
//           so wn=0 waves own (u[k'],u[2047-k']) and wn=1 (u[1023-k'],
//           u[1024+k']) LANE-ALIGNED (mirror strips staged in reversed row
//           order via per-lane global addresses).
//   PQ seg: fused P,Q loop, each 256x64, K=1024, B cols [S1' fwd|S2' rev].
// Epilogue computes the full two-level fold from registers (u +- (p+-q)) and
// writes y once — identical formulas to the verified combine_kernel.
// 256 identical 201-MF blocks = exactly 1/CU, perfectly balanced.
// Per segment: the proven R13 4-phase skeleton. PQ loop stages Ap,Bp,Aq,Bq
// with counted vmcnt(5) at p2/p4 (FIFO: drains exactly the tile needed one
// phase later; every staged load gets >=2 phases before its drain).
// LDS 144KB: Ap dbuf 64K | Aq dbuf 64K | B 16K (U reuses Ap+B regions).
// acc = 128 AGPR (u 64 + p 32 + q 32) + ~100 VGPR < 256 budget (R10's spill
// was at 256 exactly; headroom remains).
// ws (44 MB): xo 16 | xee 8 | xeo 8 | Bo 8 | Bp 2 | Bq 2. prep unchanged.

#define NN 4096

typedef __attribute__((ext_vector_type(8))) short short8;
typedef __attribute__((ext_vector_type(4))) float f32x4;

__device__ __forceinline__ unsigned short f2bf(float f) {
  unsigned int u = __float_as_uint(f);
  u += 0x7fffu + ((u >> 16) & 1u);
  return (unsigned short)(u >> 16);
}

__device__ __forceinline__ void async_load16(const void* g, void* lds) {
  __builtin_amdgcn_global_load_lds(
      (const __attribute__((address_space(1))) unsigned int*)g,
      (__attribute__((address_space(3))) unsigned int*)lds, 16, 0, 0);
}

#define NXS (NN * NN / 8)        // 2M x-split threads (8 floats each)
#define NBO (2048 * 2048 / 4)    // 1M Bo threads
#define NBP (1024 * 1024 / 4)    // 256K Bp threads (Bq same)

// prep: xo[r][m]=x[r][2m+1]; xee[r][t]=x[r][4t]; xeo[r][t]=x[r][4t+2];
// Bo[c][m]=sin(pi(2m+1)(2c+1)/8192); Bp[c][t]=sin(pi*t*(2c+1)/2048);
// Bq[c][t]=sin(pi(2t+1)(2c+1)/4096)
__global__ void prep_kernel(const float* __restrict__ x,
                            unsigned short* __restrict__ xo,
                            unsigned short* __restrict__ xee,
                            unsigned short* __restrict__ xeo,
                            unsigned short* __restrict__ Bo,
                            unsigned short* __restrict__ Bp,
                            unsigned short* __restrict__ Bq) {
  int gi = blockIdx.x * blockDim.x + threadIdx.x;
  if (gi < NXS) {
    int g = gi & 511;            // 8-float group in row
    int r = gi >> 9;
    const float4* src = (const float4*)(x + (size_t)r * NN + g * 8);
    float4 v0 = src[0], v1 = src[1];    // n = 8g+0..3, 8g+4..7
    ushort4 ov;                          // odd n -> m = 4g..4g+3
    ov.x = f2bf(v0.y); ov.y = f2bf(v0.w); ov.z = f2bf(v1.y); ov.w = f2bf(v1.w);
    *(ushort4*)&xo[(size_t)r * 2048 + g * 4] = ov;
    unsigned int ee = ((unsigned)f2bf(v1.x) << 16) | f2bf(v0.x);  // t=2g,2g+1
    *(unsigned int*)&xee[(size_t)r * 1024 + g * 2] = ee;
    unsigned int eo = ((unsigned)f2bf(v1.z) << 16) | f2bf(v0.z);
    *(unsigned int*)&xeo[(size_t)r * 1024 + g * 2] = eo;
  } else if (gi < NXS + NBO) {
    int i = gi - NXS;
    int m0 = (i & 511) * 4;
    int c = i >> 9;
    unsigned int tw = 2u * (unsigned)c + 1u;
    const float sc = 3.14159265358979323846f / 8192.0f;
    ushort4 o; unsigned int ph;
    ph = ((unsigned)(2 * (m0 + 0) + 1) * tw) & 16383u; o.x = f2bf(__sinf((float)ph * sc));
    ph = ((unsigned)(2 * (m0 + 1) + 1) * tw) & 16383u; o.y = f2bf(__sinf((float)ph * sc));
    ph = ((unsigned)(2 * (m0 + 2) + 1) * tw) & 16383u; o.z = f2bf(__sinf((float)ph * sc));
    ph = ((unsigned)(2 * (m0 + 3) + 1) * tw) & 16383u; o.w = f2bf(__sinf((float)ph * sc));
    *(ushort4*)&Bo[(size_t)c * 2048 + m0] = o;
  } else if (gi < NXS + NBO + NBP) {
    int i = gi - NXS - NBO;
    int t0 = (i & 255) * 4;
    int c = i >> 8;
    unsigned int tw = 2u * (unsigned)c + 1u;
    const float sc = 3.14159265358979323846f / 2048.0f;
    ushort4 o; unsigned int ph;
    ph = ((unsigned)(t0 + 0) * tw) & 4095u; o.x = f2bf(__sinf((float)ph * sc));
    ph = ((unsigned)(t0 + 1) * tw) & 4095u; o.y = f2bf(__sinf((float)ph * sc));
    ph = ((unsigned)(t0 + 2) * tw) & 4095u; o.z = f2bf(__sinf((float)ph * sc));
    ph = ((unsigned)(t0 + 3) * tw) & 4095u; o.w = f2bf(__sinf((float)ph * sc));
    *(ushort4*)&Bp[(size_t)c * 1024 + t0] = o;
  } else {
    int i = gi - NXS - NBO - NBP;
    int t0 = (i & 255) * 4;
    int c = i >> 8;
    unsigned int tw = 2u * (unsigned)c + 1u;
    const float sc = 3.14159265358979323846f / 4096.0f;
    ushort4 o; unsigned int ph;
    ph = ((unsigned)(2 * (t0 + 0) + 1) * tw) & 8191u; o.x = f2bf(__sinf((float)ph * sc));
    ph = ((unsigned)(2 * (t0 + 1) + 1) * tw) & 8191u; o.y = f2bf(__sinf((float)ph * sc));
    ph = ((unsigned)(2 * (t0 + 2) + 1) * tw) & 8191u; o.z = f2bf(__sinf((float)ph * sc));
    ph = ((unsigned)(2 * (t0 + 3) + 1) * tw) & 8191u; o.w = f2bf(__sinf((float)ph * sc));
    *(ushort4*)&Bq[(size_t)c * 1024 + t0] = o;
  }
}

// ---- LDS layout (ushort indices) ----------------------------------------
// Ap buf0 [0,16384) | Ap buf1 [16384,32768) | Aq buf0 [32768,49152) |
// Aq buf1 [49152,65536) | B half0 [65536,69632) | B half1 [69632,73728).
// U segment uses Ap bufs + both B halves (128 cols); PQ uses all.
#define PH_BAR  __builtin_amdgcn_s_barrier()
#define W_LGKM0 asm volatile("s_waitcnt lgkmcnt(0)" ::: "memory")
#define W_VM5   asm volatile("s_waitcnt vmcnt(5)" ::: "memory")
#define W_VM0   asm volatile("s_waitcnt vmcnt(0)" ::: "memory")
#define PRIO1   __builtin_amdgcn_s_setprio(1)
#define PRIO0   __builtin_amdgcn_s_setprio(0)

// Stage a 128-row x 64-k A half-tile (16KB, 2 loads/thread). Linear LDS dest;
// source chunk pre-swizzled by the chunk^(row&7) involution the reads apply.
#define STAGEA_G(Abase, Kc, prow0, koff, off) do {                              \
    const unsigned short* _s =                                                  \
        (Abase) + (size_t)((prow0) + st_r) * (Kc) + (koff) + st_c;              \
    async_load16(_s, &lds[(off) + tid * 8]);                                    \
    async_load16(_s + (size_t)64 * (Kc), &lds[(off) + 4096 + tid * 8]);         \
  } while (0)

// Stage one 64-col B chunk (8KB, 1 load/thread) from a precomputed per-thread
// row pointer (strip-gather with mirror strips in reversed order).
#define STAGEB_P(srcp, koff, off)                                               \
    async_load16((srcp) + (koff), &lds[(off) + tid * 8])

// A-frags for row-half mh of A buffer b at LDS base `base`: 4 ds_read_b128.
#define LOADA_G(base, b, mh) do {                                               \
    const int _ab = (base) + (b) * 16384 + wm * 4096 + (mh) * 2048 + lr * 64;   \
    _Pragma("unroll") for (int _i = 0; _i < 2; ++_i) {                          \
      av[(mh) * 2 + _i][0] = *(const short8*)&lds[_ab + _i * 1024 + cA0];       \
      av[(mh) * 2 + _i][1] = *(const short8*)&lds[_ab + _i * 1024 + cA1];       \
    }                                                                           \
  } while (0)

// U B-frags for col-half nh (32 of the wave's 64 cols): 4 ds_read_b128.
#define LOADB_U(SET, nh) do {                                                   \
    const int _bb = 65536 + wn * 4096 + (nh) * 2048 + lr * 64;                  \
    _Pragma("unroll") for (int _j = 0; _j < 2; ++_j) {                          \
      SET[_j][0] = *(const short8*)&lds[_bb + _j * 1024 + cA0];                 \
      SET[_j][1] = *(const short8*)&lds[_bb + _j * 1024 + cA1];                 \
    }                                                                           \
  } while (0)

// PQ B-frags (wave's 32 cols of a 64-col B chunk at `base`): 4 ds_read_b128.
#define LOADB_PQ(SET, base) do {                                                \
    const int _bb = (base) + wn * 2048 + lr * 64;                               \
    _Pragma("unroll") for (int _j = 0; _j < 2; ++_j) {                          \
      SET[_j][0] = *(const short8*)&lds[_bb + _j * 1024 + cA0];                 \
      SET[_j][1] = *(const short8*)&lds[_bb + _j * 1024 + cA1];                 \
    }                                                                           \
  } while (0)

// U quadrant (32x32) x K=64: 8 MFMA into uacc.
#define MMAQ_U(BS, mh, nh) do {                                                 \
    _Pragma("unroll") for (int _k = 0; _k < 2; ++_k)                            \
    _Pragma("unroll") for (int _i = 0; _i < 2; ++_i)                            \
    _Pragma("unroll") for (int _j = 0; _j < 2; ++_j)                            \
      uacc[(mh) * 2 + _i][(nh) * 2 + _j] =                                      \
          __builtin_amdgcn_mfma_f32_16x16x32_bf16(                              \
              av[(mh) * 2 + _i][_k], BS[_j][_k],                                \
              uacc[(mh) * 2 + _i][(nh) * 2 + _j], 0, 0, 0);                     \
  } while (0)

// P/Q half (32 rows x 32 cols) x K=64: 8 MFMA into ACC.
#define MMAQ_PQ(ACC, BS, mh) do {                                               \
    _Pragma("unroll") for (int _k = 0; _k < 2; ++_k)                            \
    _Pragma("unroll") for (int _i = 0; _i < 2; ++_i)                            \
    _Pragma("unroll") for (int _j = 0; _j < 2; ++_j)                            \
      ACC[(mh) * 2 + _i][_j] =                                                  \
          __builtin_amdgcn_mfma_f32_16x16x32_bf16(                              \
              av[(mh) * 2 + _i][_k], BS[_j][_k],                                \
              ACC[(mh) * 2 + _i][_j], 0, 0, 0);                                 \
  } while (0)

__global__ __launch_bounds__(512) void gemm3_kernel(
    const unsigned short* __restrict__ xo,
    const unsigned short* __restrict__ xee,
    const unsigned short* __restrict__ xeo,
    const unsigned short* __restrict__ Bo,
    const unsigned short* __restrict__ Bp,
    const unsigned short* __restrict__ Bq,
    float* __restrict__ out) {
  __shared__ __align__(16) unsigned short lds[73728];   // 144 KiB

  const int bx = blockIdx.x;           // 256 identical blocks
  const int row0 = (bx & 15) * 256;
  const int c0 = (bx >> 4) * 32;       // quad-group base k'

  const int tid = threadIdx.x;
  const int lane = tid & 63;
  const int wave = tid >> 6;
  const int wm = wave >> 1;            // 0..3 : 64-row strip
  const int wn = wave & 1;             // 0..1 : col-half (strip pair)
  const int lr = lane & 15, kq = lane >> 4;
  const int st_r = tid >> 3;                         // staging row 0..63
  const int st_c = ((tid & 7) ^ (st_r & 7)) * 8;     // pre-swizzled src chunk
  const int cA0 = (kq ^ (lr & 7)) * 8;               // swizzled ds_read chunks
  const int cA1 = ((4 + kq) ^ (lr & 7)) * 8;

  // Per-thread B staging row pointers (strip-gather; mirrors reversed).
  const int ru0 = (st_r < 32) ? (c0 + st_r) : (2047 - c0 - (st_r - 32));
  const int ru1 = (st_r < 32) ? (1023 - c0 - st_r) : (1024 + c0 + (st_r - 32));
  const int rpq = (st_r < 32) ? (c0 + st_r) : (1023 - c0 - (st_r - 32));
  const unsigned short* sBo0 = Bo + (size_t)ru0 * 2048 + st_c;
  const unsigned short* sBo1 = Bo + (size_t)ru1 * 2048 + st_c;
  const unsigned short* sBp  = Bp + (size_t)rpq * 1024 + st_c;
  const unsigned short* sBq  = Bq + (size_t)rpq * 1024 + st_c;

  f32x4 uacc[4][4], pacc[4][2], qacc[4][2];
#pragma unroll
  for (int i = 0; i < 4; ++i) {
#pragma unroll
    for (int j = 0; j < 4; ++j) uacc[i][j] = (f32x4){0.f, 0.f, 0.f, 0.f};
#pragma unroll
    for (int j = 0; j < 2; ++j) {
      pacc[i][j] = (f32x4){0.f, 0.f, 0.f, 0.f};
      qacc[i][j] = (f32x4){0.f, 0.f, 0.f, 0.f};
    }
  }
  short8 av[4][2], bv0[2][2], bv1[2][2];

  // ================= U segment: 256x128, K=2048, 32 K-tiles ================
  STAGEA_G(xo, 2048, row0,       0, 0);
  STAGEA_G(xo, 2048, row0 + 128, 0, 8192);
  STAGEB_P(sBo0, 0, 65536);
  STAGEB_P(sBo1, 0, 69632);
  W_VM0; PH_BAR;

  for (int it = 0; it < 15; ++it) {
    const int t64 = it << 7;
    // tile t (buf0)
    LOADA_G(0, 0, 0); LOADB_U(bv0, 0);
    STAGEA_G(xo, 2048, row0, t64 + 64, 16384);
    PH_BAR; W_LGKM0; PRIO1; MMAQ_U(bv0, 0, 0); PRIO0; PH_BAR;
    LOADB_U(bv1, 1);
    STAGEA_G(xo, 2048, row0 + 128, t64 + 64, 24576);
    PH_BAR; W_LGKM0; PRIO1; MMAQ_U(bv1, 0, 1); PRIO0; PH_BAR;
    LOADA_G(0, 0, 1);
    STAGEB_P(sBo0, t64 + 64, 65536);
    STAGEB_P(sBo1, t64 + 64, 69632);
    PH_BAR; W_LGKM0; PRIO1; MMAQ_U(bv1, 1, 1); PRIO0; PH_BAR;
    PRIO1; MMAQ_U(bv0, 1, 0); PRIO0; W_VM0; PH_BAR;
    // tile t+1 (buf1)
    LOADA_G(0, 1, 0); LOADB_U(bv0, 0);
    STAGEA_G(xo, 2048, row0, t64 + 128, 0);
    PH_BAR; W_LGKM0; PRIO1; MMAQ_U(bv0, 0, 0); PRIO0; PH_BAR;
    LOADB_U(bv1, 1);
    STAGEA_G(xo, 2048, row0 + 128, t64 + 128, 8192);
    PH_BAR; W_LGKM0; PRIO1; MMAQ_U(bv1, 0, 1); PRIO0; PH_BAR;
    LOADA_G(0, 1, 1);
    STAGEB_P(sBo0, t64 + 128, 65536);
    STAGEB_P(sBo1, t64 + 128, 69632);
    PH_BAR; W_LGKM0; PRIO1; MMAQ_U(bv1, 1, 1); PRIO0; PH_BAR;
    PRIO1; MMAQ_U(bv0, 1, 0); PRIO0; W_VM0; PH_BAR;
  }
  { // peel tiles 30 (buf0) + 31 (buf1)
    LOADA_G(0, 0, 0); LOADB_U(bv0, 0);
    STAGEA_G(xo, 2048, row0, 1984, 16384);
    PH_BAR; W_LGKM0; PRIO1; MMAQ_U(bv0, 0, 0); PRIO0; PH_BAR;
    LOADB_U(bv1, 1);
    STAGEA_G(xo, 2048, row0 + 128, 1984, 24576);
    PH_BAR; W_LGKM0; PRIO1; MMAQ_U(bv1, 0, 1); PRIO0; PH_BAR;
    LOADA_G(0, 0, 1);
    STAGEB_P(sBo0, 1984, 65536);
    STAGEB_P(sBo1, 1984, 69632);
    PH_BAR; W_LGKM0; PRIO1; MMAQ_U(bv1, 1, 1); PRIO0; PH_BAR;
    PRIO1; MMAQ_U(bv0, 1, 0); PRIO0; W_VM0; PH_BAR;
    LOADA_G(0, 1, 0); LOADB_U(bv0, 0);
    W_LGKM0; PRIO1; MMAQ_U(bv0, 0, 0); PRIO0;
    LOADB_U(bv1, 1);
    W_LGKM0; PRIO1; MMAQ_U(bv1, 0, 1); PRIO0;
    LOADA_G(0, 1, 1);
    W_LGKM0; PRIO1; MMAQ_U(bv1, 1, 1); MMAQ_U(bv0, 1, 0); PRIO0;
  }

  // ============== PQ segment: fused P,Q loops, K=1024, 16 K-tiles ==========
  PH_BAR;   // all waves done reading U's B region before Bp lands there
  STAGEA_G(xee, 1024, row0,       0, 0);
  STAGEA_G(xee, 1024, row0 + 128, 0, 8192);
  STAGEB_P(sBp, 0, 65536);
  STAGEA_G(xeo, 1024, row0,       0, 32768);
  STAGEA_G(xeo, 1024, row0 + 128, 0, 40960);
  STAGEB_P(sBq, 0, 69632);
  W_VM5; PH_BAR;   // drains Ap[0]+Bp[0]; leaves Aq[0](4)+Bq[0](1) in flight

// One PQ K-tile t in buffer b; stages tile t+1 (koff kn) into buffer b^1.
#define PQ_TILE(b, kn) do {                                                     \
    LOADA_G(0, b, 0); LOADB_PQ(bv0, 65536);                                     \
    STAGEA_G(xee, 1024, row0, kn, ((b) ^ 1) * 16384);                           \
    PH_BAR; W_LGKM0; PRIO1; MMAQ_PQ(pacc, bv0, 0); PRIO0; PH_BAR;               \
    LOADA_G(0, b, 1);                                                           \
    STAGEA_G(xee, 1024, row0 + 128, kn, ((b) ^ 1) * 16384 + 8192);              \
    STAGEB_P(sBp, kn, 65536);                                                   \
    PH_BAR; W_LGKM0; PRIO1; MMAQ_PQ(pacc, bv0, 1); PRIO0; W_VM5; PH_BAR;        \
    LOADA_G(32768, b, 0); LOADB_PQ(bv1, 69632);                                 \
    STAGEA_G(xeo, 1024, row0, kn, 32768 + ((b) ^ 1) * 16384);                   \
    PH_BAR; W_LGKM0; PRIO1; MMAQ_PQ(qacc, bv1, 0); PRIO0; PH_BAR;               \
    LOADA_G(32768, b, 1);                                                       \
    STAGEA_G(xeo, 1024, row0 + 128, kn, 32768 + ((b) ^ 1) * 16384 + 8192);      \
    STAGEB_P(sBq, kn, 69632);                                                   \
    PH_BAR; W_LGKM0; PRIO1; MMAQ_PQ(qacc, bv1, 1); PRIO0; W_VM5; PH_BAR;        \
  } while (0)

  for (int it = 0; it < 7; ++it) {       // tiles 0..13
    const int t64 = it << 7;
    PQ_TILE(0, t64 + 64);
    PQ_TILE(1, t64 + 128);
  }
  PQ_TILE(0, 960);                       // tile 14, stages tile 15
  { // peel tile 15 (buf1)
    LOADA_G(0, 1, 0); LOADB_PQ(bv0, 65536);
    W_LGKM0; PRIO1; MMAQ_PQ(pacc, bv0, 0); PRIO0;
    LOADA_G(0, 1, 1);
    W_LGKM0; PRIO1; MMAQ_PQ(pacc, bv0, 1); PRIO0; W_VM0; PH_BAR;
    LOADA_G(32768, 1, 0); LOADB_PQ(bv1, 69632);
    W_LGKM0; PRIO1; MMAQ_PQ(qacc, bv1, 0); PRIO0;
    LOADA_G(32768, 1, 1);
    W_LGKM0; PRIO1; MMAQ_PQ(qacc, bv1, 1); PRIO0;
  }
#undef PQ_TILE

  // ===================== epilogue: full two-level fold =====================
  // C/D layout: col=lane&15 within fragment, row=kq*4+rr.
  // wn=0: u1=u[k'], u4=u[2047-k'], p/q at k'.  wn=1: u1=u[1023-k'],
  // u4=u[1024+k'], p/q at 1023-k'.  k' = c0+cs, cs = j*16+lr.
#pragma unroll
  for (int i = 0; i < 4; ++i)
#pragma unroll
    for (int j = 0; j < 2; ++j)
#pragma unroll
      for (int rr = 0; rr < 4; ++rr) {
        const int r_out = row0 + wm * 64 + i * 16 + kq * 4 + rr;
        float* orow = out + (size_t)r_out * NN;
        const int cs = j * 16 + lr;
        const float u1 = uacc[i][j][rr];
        const float u4 = uacc[i][j + 2][rr];
        const float pa = pacc[i][j][rr];
        const float qa = qacc[i][j][rr];
        const float v1 = pa + qa;
        const float v2 = qa - pa;
        if (wn == 0) {
          orow[c0 + cs]        = v1 + u1;   // y[k']
          orow[4095 - c0 - cs] = u1 - v1;   // y[4095-k']
          orow[2047 - c0 - cs] = v2 + u4;   // y[2047-k']
          orow[2048 + c0 + cs] = u4 - v2;   // y[2048+k']
        } else {
          orow[1023 - c0 - cs] = v1 + u1;   // y[1023-k']
          orow[3072 + c0 + cs] = u1 - v1;   // y[3072+k']
          orow[1024 + c0 + cs] = v2 + u4;   // y[1024+k']
          orow[3071 - c0 - cs] = u4 - v2;   // y[3071-k']
        }
      }
}

extern "C" void kernel_launch(void* const* d_in, const int* in_sizes, int n_in,
                              void* d_out, int out_size, void* d_ws, size_t ws_size,
                              hipStream_t stream) {
  const float* x = (const float*)d_in[0];
  float* out = (float*)d_out;
  unsigned short* xo  = (unsigned short*)d_ws;            // 16 MB
  unsigned short* xee = xo + (size_t)NN * 2048;           // 8 MB
  unsigned short* xeo = xee + (size_t)NN * 1024;          // 8 MB
  unsigned short* Bo  = xeo + (size_t)NN * 1024;          // 8 MB
  unsigned short* Bp  = Bo + (size_t)2048 * 2048;         // 2 MB
  unsigned short* Bq  = Bp + (size_t)1024 * 1024;         // 2 MB -> 44 MB total

  int prep_threads = NXS + NBO + 2 * NBP;
  prep_kernel<<<prep_threads / 256, 256, 0, stream>>>(x, xo, xee, xeo, Bo, Bp, Bq);

  gemm3_kernel<<<256, 512, 0, stream>>>(xo, xee, xeo, Bo, Bp, Bq, out);
}